// Round 16
// baseline (257.671 us; speedup 1.0000x reference)
//
#include <hip/hip_runtime.h>

#define B_   2
#define T_   2048
#define C_   768
#define H_   12
#define HD_  64
#define M_   (B_ * T_)    // 4096 rows
#define N3_  (3 * C_)     // 2304
#define KB_  (C_ * 2)     // 1536 bytes per row (bf16)

typedef __bf16 bf16_t;
typedef bf16_t bf16x8 __attribute__((ext_vector_type(8)));
typedef float  floatx4 __attribute__((ext_vector_type(4)));

__device__ inline floatx4 mfma_bf16(bf16x8 a, bf16x8 b, floatx4 c) {
    return __builtin_amdgcn_mfma_f32_16x16x32_bf16(a, b, c, 0, 0, 0);
}

__device__ __forceinline__ void async_copy16(const void* g, void* l) {
    __builtin_amdgcn_global_load_lds(
        (const __attribute__((address_space(1))) void*)g,
        (__attribute__((address_space(3))) void*)l, 16, 0, 0);
}

__device__ __forceinline__ bf16x8 frag_read(const char* ldsbase, int row, int quad) {
    int slot = quad ^ ((row >> 1) & 3);
    return *(const bf16x8*)(ldsbase + row * 64 + slot * 16);
}

// ---------------------------------------------------------------------------
// 128x128-tile GEMM mainloop, DOUBLE-BUFFERED, 512 THREADS (8 waves).
// ---------------------------------------------------------------------------
template<bool TRIPLE>
__device__ __forceinline__ void gemm_loop8(
    const char* Ah, const char* Al, const char* Bh, const char* Bl,
    char* lds, floatx4 (&acc)[4][2])
{
    int tid = threadIdx.x, lane = tid & 63, wave = tid >> 6;
    int l15 = lane & 15, quad = lane >> 4;
    int wr = wave >> 2, wc = wave & 3;
    const int PH = TRIPLE ? 32768 : 16384;
    auto stage1 = [&](const char* tile, char* base, int k0) {
        int p = tid;                             // 512 x 16B = 8 KB
        int r = p >> 2, slot = p & 3;
        int g = slot ^ ((r >> 1) & 3);
        async_copy16(tile + (size_t)r * KB_ + k0 + g * 16, base + p * 16);
    };
    auto stage = [&](int ph, int k0) {
        char* base = lds + ph * PH;
        stage1(Ah, base, k0);
        stage1(Bh, base + 8192, k0);
        if (TRIPLE) {
            stage1(Al, base + 16384, k0);
            stage1(Bl, base + 24576, k0);
        }
    };
    stage(0, 0);
    int ph = 0;
#pragma unroll 1
    for (int k0 = 0; k0 < KB_; k0 += 64) {       // 32 bf16 per chunk
        __syncthreads();                          // drains stage(ph)
        if (k0 + 64 < KB_) stage(ph ^ 1, k0 + 64);
        char* base = lds + ph * PH;
        bf16x8 ah[4], al[4], bh[2], bl[2];
#pragma unroll
        for (int t = 0; t < 4; ++t) {
            ah[t] = frag_read(base, wr * 64 + t * 16 + l15, quad);
            if (TRIPLE)
                al[t] = frag_read(base + 16384, wr * 64 + t * 16 + l15, quad);
        }
#pragma unroll
        for (int t = 0; t < 2; ++t) {
            bh[t] = frag_read(base + 8192, wc * 32 + t * 16 + l15, quad);
            if (TRIPLE)
                bl[t] = frag_read(base + 24576, wc * 32 + t * 16 + l15, quad);
        }
#pragma unroll
        for (int mi = 0; mi < 4; ++mi)
#pragma unroll
            for (int ni = 0; ni < 2; ++ni) {
                acc[mi][ni] = mfma_bf16(ah[mi], bh[ni], acc[mi][ni]);
                if (TRIPLE) {
                    acc[mi][ni] = mfma_bf16(ah[mi], bl[ni], acc[mi][ni]);
                    acc[mi][ni] = mfma_bf16(al[mi], bh[ni], acc[mi][ni]);
                }
            }
        ph ^= 1;
    }
}

// ---------------------------------------------------------------------------
// K0 (fused): split x -> x_hi/lo, split w_attn -> w_hi/lo, convert w_proj.
// ---------------------------------------------------------------------------
__global__ __launch_bounds__(256) void prep_kernel(
    const float* __restrict__ x, const float* __restrict__ w_attn,
    const float* __restrict__ w_proj,
    bf16_t* __restrict__ x_hi, bf16_t* __restrict__ x_lo,
    bf16_t* __restrict__ w_hi, bf16_t* __restrict__ w_lo,
    bf16_t* __restrict__ wp_b, int nx, int nw, int np)
{
    int gid = blockIdx.x * 256 + threadIdx.x;
    if (gid < nx) {
        float f = x[gid];
        bf16_t h = (bf16_t)f;
        x_hi[gid] = h;
        x_lo[gid] = (bf16_t)(f - (float)h);
    } else if (gid < nx + nw) {
        int i = gid - nx;
        float f = w_attn[i];
        bf16_t h = (bf16_t)f;
        w_hi[i] = h;
        w_lo[i] = (bf16_t)(f - (float)h);
    } else if (gid < nx + nw + np) {
        int i = gid - nx - nw;
        wp_b[i] = (bf16_t)w_proj[i];
    }
}

// ---------------------------------------------------------------------------
// K1: qkv = x @ w_attn^T + b_attn (512 threads).  q/k bf16x3; v bf16.
// q stored PRE-SCALED by 0.125.  Section is BLOCK-uniform (768 % 128 == 0).
// ---------------------------------------------------------------------------
__global__ __launch_bounds__(512) void qkv_gemm(
    const bf16_t* __restrict__ x_hi, const bf16_t* __restrict__ x_lo,
    const bf16_t* __restrict__ w_hi, const bf16_t* __restrict__ w_lo,
    const float* __restrict__ bias, const float* __restrict__ selw,
    bf16_t* __restrict__ q_hi, bf16_t* __restrict__ q_lo,
    bf16_t* __restrict__ kw_hi, bf16_t* __restrict__ kw_lo,
    bf16_t* __restrict__ k_b, bf16_t* __restrict__ v_b)
{
    extern __shared__ char lds[];
    int m0 = blockIdx.x * 128, n0 = blockIdx.y * 128;
    floatx4 acc[4][2];
#pragma unroll
    for (int i = 0; i < 4; ++i)
#pragma unroll
        for (int j = 0; j < 2; ++j) acc[i][j] = (floatx4){0.f, 0.f, 0.f, 0.f};
    if (n0 >= 2 * C_) {   // v section: single-precision bf16 path
        gemm_loop8<false>((const char*)(x_hi + (size_t)m0 * C_), nullptr,
                          (const char*)(w_hi + (size_t)n0 * C_), nullptr, lds, acc);
    } else {
        gemm_loop8<true>((const char*)(x_hi + (size_t)m0 * C_),
                         (const char*)(x_lo + (size_t)m0 * C_),
                         (const char*)(w_hi + (size_t)n0 * C_),
                         (const char*)(w_lo + (size_t)n0 * C_), lds, acc);
    }

    int tid = threadIdx.x, lane = tid & 63, wave = tid >> 6;
    int l15 = lane & 15, quad = lane >> 4;
    int wr = wave >> 2, wc = wave & 3;
    int cb = n0 + wc * 32;
#pragma unroll
    for (int ni = 0; ni < 2; ++ni) {
        int col = cb + ni * 16 + l15;
        float bb = bias[col];
#pragma unroll
        for (int mi = 0; mi < 4; ++mi)
#pragma unroll
            for (int r = 0; r < 4; ++r) {
                int row = m0 + wr * 64 + mi * 16 + quad * 4 + r;
                float v = acc[mi][ni][r] + bb;
                if (cb < C_) {
                    float vs = v * 0.125f;           // fold softmax scale
                    bf16_t h = (bf16_t)vs;
                    q_hi[(size_t)row * C_ + col] = h;
                    q_lo[(size_t)row * C_ + col] = (bf16_t)(vs - (float)h);
                } else if (cb < 2 * C_) {
                    int c2 = col - C_;
                    k_b[(size_t)row * C_ + c2] = (bf16_t)v;
                    float kw = v * selw[c2 >> 6];
                    bf16_t h = (bf16_t)kw;
                    kw_hi[(size_t)row * C_ + c2] = h;
                    kw_lo[(size_t)row * C_ + c2] = (bf16_t)(kw - (float)h);
                } else {
                    v_b[(size_t)row * C_ + (col - 2 * C_)] = (bf16_t)v;
                }
            }
    }
}

// ---------------------------------------------------------------------------
// K2: triangular s_gemm (512 threads), lower-triangle tiles (136/batch),
// fused segsum.
// ---------------------------------------------------------------------------
#define SEG_    16
#define SEGLEN_ (T_ / SEG_)  // 128

__global__ __launch_bounds__(512) void s_gemm(
    const bf16_t* __restrict__ q_hi, const bf16_t* __restrict__ q_lo,
    const bf16_t* __restrict__ kw_hi, const bf16_t* __restrict__ kw_lo,
    float* __restrict__ SF, float* __restrict__ segsum)
{
    extern __shared__ char lds[];
    int t = blockIdx.x, b = blockIdx.z;
    int it = (int)((sqrtf(8.f * t + 1.f) - 1.f) * 0.5f);
    while ((it + 1) * (it + 2) / 2 <= t) ++it;
    while (it * (it + 1) / 2 > t) --it;
    int jt = t - it * (it + 1) / 2;               // jt <= it
    int i0 = it * 128, j0 = jt * 128;
    float* out = SF + (size_t)b * T_ * T_;

    floatx4 acc[4][2];
#pragma unroll
    for (int i = 0; i < 4; ++i)
#pragma unroll
        for (int j = 0; j < 2; ++j) acc[i][j] = (floatx4){0.f, 0.f, 0.f, 0.f};
    size_t arow = ((size_t)b * T_ + i0) * C_;
    size_t brow = ((size_t)b * T_ + j0) * C_;
    gemm_loop8<true>((const char*)(q_hi + arow), (const char*)(q_lo + arow),
                     (const char*)(kw_hi + brow), (const char*)(kw_lo + brow),
                     lds, acc);

    int tid = threadIdx.x, lane = tid & 63, wave = tid >> 6;
    int l15 = lane & 15, quad = lane >> 4;
    int wr = wave >> 2, wc = wave & 3;
    float colsum[2] = {0.f, 0.f};
#pragma unroll
    for (int ni = 0; ni < 2; ++ni) {
        int j = j0 + wc * 32 + ni * 16 + l15;
#pragma unroll
        for (int mi = 0; mi < 4; ++mi)
#pragma unroll
            for (int r = 0; r < 4; ++r) {
                int i = i0 + wr * 64 + mi * 16 + quad * 4 + r;
                float s = acc[mi][ni][r];
                s = (j >= 1 && j < i) ? fmaxf(s, 0.f) : 0.f;
                out[(size_t)i * T_ + j] = s;
                colsum[ni] += s;
            }
    }
#pragma unroll
    for (int ni = 0; ni < 2; ++ni) {
        colsum[ni] += __shfl_xor(colsum[ni], 16);
        colsum[ni] += __shfl_xor(colsum[ni], 32);
    }
    float* red = (float*)lds;                     // [wr][128] (phase-0 area)
    if (quad == 0) {
#pragma unroll
        for (int ni = 0; ni < 2; ++ni)
            red[wr * 128 + wc * 32 + ni * 16 + l15] = colsum[ni];
    }
    __syncthreads();
    if (tid < 128) {
        float ssum = red[tid] + red[128 + tid];
        segsum[((size_t)b * SEG_ + it) * T_ + j0 + tid] = ssum;
    }
}

// ---------------------------------------------------------------------------
// K4: scan_apply with inline exclusive segment prefix from raw segsum.
// ---------------------------------------------------------------------------
__global__ __launch_bounds__(256) void scan_apply(
    float* __restrict__ SF, const float* __restrict__ segsum)
{
    int gid  = blockIdx.x * 256 + threadIdx.x;
    int j    = gid & (T_ - 1);
    int rest = gid >> 11;
    int seg  = rest & (SEG_ - 1);
    int b    = rest >> 4;
    if (seg * SEGLEN_ + SEGLEN_ - 1 < j) return;   // no row i>=j here; never read
    float run = 0.f;
    for (int s = 0; s < seg; ++s) {
        float v = (s * SEGLEN_ + SEGLEN_ - 1 <= j) ? 0.f
                : segsum[((size_t)b * SEG_ + s) * T_ + j];
        run += v;
    }
    float* col = SF + (size_t)b * T_ * T_ + (size_t)(seg * SEGLEN_) * T_ + j;
#pragma unroll 4
    for (int i = 0; i < SEGLEN_; ++i) {
        float s = col[(size_t)i * T_];
        s = (seg * SEGLEN_ + i > j) ? s : 0.f;     // upper-tri SF is unwritten
        col[(size_t)i * T_] = run;                 // exclusive: FF_shifted
        run += s;
    }
}

// ---------------------------------------------------------------------------
// K5b: V -> V^T  (per (b,h): [T][64] -> [64][T]).
// ---------------------------------------------------------------------------
__global__ __launch_bounds__(256) void vt_kernel(
    const bf16_t* __restrict__ v_b, bf16_t* __restrict__ vt)
{
    __shared__ bf16_t tile[64][72];
    int t0 = blockIdx.x * 64, h = blockIdx.y, b = blockIdx.z;
    int tid = threadIdx.x;
    int r = tid >> 2, sl = tid & 3;
    const bf16_t* src = v_b + ((size_t)(b * T_ + t0 + r)) * C_ + h * HD_ + sl * 16;
    *(int4*)&tile[r][sl * 16]     = *(const int4*)src;
    *(int4*)&tile[r][sl * 16 + 8] = *(const int4*)(src + 8);
    __syncthreads();
    int hd = tid >> 2, q = tid & 3;
#pragma unroll
    for (int half = 0; half < 2; ++half) {
        int c0 = (q * 2 + half) * 8;
        union { int4 i4; bf16_t e[8]; } u;
#pragma unroll
        for (int kk = 0; kk < 8; ++kk) u.e[kk] = tile[c0 + kk][hd];
        *(int4*)(vt + ((size_t)(b * H_ + h) * HD_ + hd) * T_ + t0 + c0) = u.i4;
    }
}

// ---------------------------------------------------------------------------
// K6: dbuf LDS flash attention + fixed-max softmax + SUM-CONSTANT CU SWIZZLE.
// Round-15 analysis: CU c hosts blocks {x=c%32, t=0,1,2} (t=(y+12z)>>3);
// the round-13 swizzle left triple-sums ranging 31..62 iters -> worst CU 63
// vs 49.5 avg.  New per-t bijections with CONSTANT triple sum (46 or 47):
//   t=0: x   t=1: (x+16)&31   t=2: x<16 ? 30-2x : 63-2x
// -> every CU runs 49-50 iterations (theoretical balance point).
// ---------------------------------------------------------------------------
__global__ __launch_bounds__(256) void attn_kernel(
    const bf16_t* __restrict__ q_b, const bf16_t* __restrict__ k_b,
    const bf16_t* __restrict__ vt_g, const float* __restrict__ FF,
    bf16_t* __restrict__ y_b)
{
    __shared__ __align__(16) char KL[2][8192];
    __shared__ __align__(16) char VL[2][8192];
    __shared__ __align__(16) float LS[4][16][68];

    int tid = threadIdx.x, lane = tid & 63, wave = tid >> 6;
    int l15 = lane & 15, quad = lane >> 4;
    int x = (int)blockIdx.x;
    int t3 = ((int)blockIdx.y + 12 * (int)blockIdx.z) >> 3;    // 0,1,2
    int bi;
    if (t3 == 0)      bi = x;
    else if (t3 == 1) bi = (x + 16) & 31;
    else              bi = (x < 16) ? (30 - 2 * x) : (63 - 2 * x);
    int h = blockIdx.y, b = blockIdx.z;
    int i0w = bi * 64 + wave * 16;
    int jmax = bi * 64 + 63;
    const floatx4 fzero = {0.f, 0.f, 0.f, 0.f};
    const float FM = 20.f;                         // fixed softmax normalizer

    const bf16_t* qrow = q_b + ((size_t)b * T_ + i0w + l15) * C_ + h * HD_;
    bf16x8 qa0 = *(const bf16x8*)(qrow + quad * 8);
    bf16x8 qa1 = *(const bf16x8*)(qrow + 32 + quad * 8);

    const bf16_t* kbase = k_b + (size_t)b * T_ * C_ + h * HD_;
    const bf16_t* vbase = vt_g + (size_t)(b * H_ + h) * HD_ * T_;
    const float*  fp    = FF + ((size_t)b * T_ + i0w + l15) * T_ + quad * 8;

    auto stage = [&](int ph, int j0) {
#pragma unroll
        for (int i = 0; i < 2; ++i) {
            int p = (wave * 2 + i) * 64 + lane;
            int r = p >> 3, sp = p & 7, s = sp ^ (r & 7);
            async_copy16(kbase + (size_t)(j0 + r) * C_ + s * 8, &KL[ph][p * 16]);
        }
#pragma unroll
        for (int i = 0; i < 2; ++i) {
            int p = (wave * 2 + i) * 64 + lane;
            int r = p >> 3, sp = p & 7, s = sp ^ (r & 7);
            async_copy16(vbase + (size_t)r * T_ + j0 + s * 8, &VL[ph][p * 16]);
        }
    };

    float l_run = 0.f;
    floatx4 O[4];
#pragma unroll
    for (int nt = 0; nt < 4; ++nt) O[nt] = fzero;

    stage(0, 0);
    int ph = 0;
#pragma unroll 1
    for (int j0 = 0; j0 <= jmax; j0 += 64) {
        __syncthreads();
        if (j0 + 64 <= jmax) stage(ph ^ 1, j0 + 64);

        float ffv[16];
        *(floatx4*)&ffv[0]  = *(const floatx4*)(fp);
        *(floatx4*)&ffv[4]  = *(const floatx4*)(fp + 4);
        *(floatx4*)&ffv[8]  = *(const floatx4*)(fp + 32);
        *(floatx4*)&ffv[12] = *(const floatx4*)(fp + 36);
        fp += 64;

        floatx4 pc[4];
#pragma unroll
        for (int s = 0; s < 4; ++s) {
            int r = s * 16 + l15;
            bf16x8 k0 = *(const bf16x8*)&KL[ph][r * 128 + ((quad     ^ (r & 7)) * 16)];
            bf16x8 k1 = *(const bf16x8*)&KL[ph][r * 128 + (((quad+4) ^ (r & 7)) * 16)];
            floatx4 p = mfma_bf16(qa0, k0, fzero);
            pc[s] = mfma_bf16(qa1, k1, p);
        }
#pragma unroll
        for (int s = 0; s < 4; ++s)
#pragma unroll
            for (int r = 0; r < 4; ++r)
                LS[wave][quad * 4 + r][s * 16 + l15] = pc[s][r];
        float qk[16];
        *(floatx4*)&qk[0]  = *(const floatx4*)&LS[wave][l15][quad * 8];
        *(floatx4*)&qk[4]  = *(const floatx4*)&LS[wave][l15][quad * 8 + 4];
        *(floatx4*)&qk[8]  = *(const floatx4*)&LS[wave][l15][32 + quad * 8];
        *(floatx4*)&qk[12] = *(const floatx4*)&LS[wave][l15][32 + quad * 8 + 4];

        float lg[16];
#pragma unroll
        for (int c = 0; c < 16; ++c) lg[c] = qk[c] - ffv[c];
        if (j0 + 63 > i0w) {
            int i = i0w + l15;
#pragma unroll
            for (int c = 0; c < 16; ++c) {
                int j = j0 + (c >> 3) * 32 + quad * 8 + (c & 7);
                lg[c] = (j <= i) ? lg[c] : -__builtin_inff();
            }
        }
        // fixed-normalizer softmax: no max-reduce, no alpha, no rescale
        float p[16], ps = 0.f;
#pragma unroll
        for (int c = 0; c < 16; ++c) { p[c] = __expf(lg[c] - FM); ps += p[c]; }
        ps += __shfl_xor(ps, 16);
        ps += __shfl_xor(ps, 32);
        l_run += ps;

        bf16x8 pa0, pa1;
#pragma unroll
        for (int c = 0; c < 8; ++c) { pa0[c] = (bf16_t)p[c]; pa1[c] = (bf16_t)p[8 + c]; }
#pragma unroll
        for (int nt = 0; nt < 4; ++nt) {
            int r = nt * 16 + l15;
            bf16x8 v0 = *(const bf16x8*)&VL[ph][r * 128 + ((quad     ^ (r & 7)) * 16)];
            bf16x8 v1 = *(const bf16x8*)&VL[ph][r * 128 + (((quad+4) ^ (r & 7)) * 16)];
            O[nt] = mfma_bf16(pa0, v0, O[nt]);
            O[nt] = mfma_bf16(pa1, v1, O[nt]);
        }
        ph ^= 1;
    }

#pragma unroll
    for (int r = 0; r < 4; ++r) {
        float inv = 1.f / __shfl(l_run, quad * 4 + r);
        int i = i0w + quad * 4 + r;
#pragma unroll
        for (int nt = 0; nt < 4; ++nt)
            y_b[((size_t)b * T_ + i) * C_ + h * HD_ + nt * 16 + l15] =
                (bf16_t)(O[nt][r] * inv);
    }
}

// ---------------------------------------------------------------------------
// K7: out = y @ w_proj^T + b_proj  (512 threads, dbuf 32 KB)
// ---------------------------------------------------------------------------
__global__ __launch_bounds__(512) void proj_gemm(
    const bf16_t* __restrict__ y_b, const bf16_t* __restrict__ wp_b,
    const float* __restrict__ bias, float* __restrict__ out)
{
    extern __shared__ char lds[];
    int m0 = blockIdx.x * 128, n0 = blockIdx.y * 128;
    floatx4 acc[4][2];
#pragma unroll
    for (int i = 0; i < 4; ++i)
#pragma unroll
        for (int j = 0; j < 2; ++j) acc[i][j] = (floatx4){0.f, 0.f, 0.f, 0.f};
    gemm_loop8<false>((const char*)(y_b + (size_t)m0 * C_), nullptr,
                      (const char*)(wp_b + (size_t)n0 * C_), nullptr, lds, acc);

    int tid = threadIdx.x, lane = tid & 63, wave = tid >> 6;
    int l15 = lane & 15, quad = lane >> 4;
    int wr = wave >> 2, wc = wave & 3;
#pragma unroll
    for (int ni = 0; ni < 2; ++ni) {
        int col = n0 + wc * 32 + ni * 16 + l15;
        float bb = bias[col];
#pragma unroll
        for (int mi = 0; mi < 4; ++mi)
#pragma unroll
            for (int r = 0; r < 4; ++r)
                out[(size_t)(m0 + wr * 64 + mi * 16 + quad * 4 + r) * C_ + col] =
                    acc[mi][ni][r] + bb;
    }
}

// ---------------------------------------------------------------------------
extern "C" void kernel_launch(void* const* d_in, const int* in_sizes, int n_in,
                              void* d_out, int out_size, void* d_ws, size_t ws_size,
                              hipStream_t stream)
{
    const float* x      = (const float*)d_in[0];
    const float* w_attn = (const float*)d_in[1];
    const float* b_attn = (const float*)d_in[2];
    const float* w_proj = (const float*)d_in[3];
    const float* b_proj = (const float*)d_in[4];
    const float* sel_w  = (const float*)d_in[5];
    float* out = (float*)d_out;

    char* ws = (char*)d_ws;
    size_t off = 0;
    auto alloc = [&](size_t bytes) {
        void* p = ws + off;
        off += (bytes + 255) & ~(size_t)255;
        return p;
    };
    const size_t MC2 = (size_t)M_ * C_ * 2;          // 6.29 MB
    // Persistent region
    bf16_t* q_hi   = (bf16_t*)alloc(MC2);
    bf16_t* q_lo   = (bf16_t*)alloc(MC2);
    bf16_t* kw_hi  = (bf16_t*)alloc(MC2);   // dead after s_gemm -> reused as vt
    bf16_t* kw_lo  = (bf16_t*)alloc(MC2);
    bf16_t* k_b    = (bf16_t*)alloc(MC2);
    bf16_t* v_b    = (bf16_t*)alloc(MC2);
    bf16_t* y_b    = (bf16_t*)alloc(MC2);
    bf16_t* wp_b   = (bf16_t*)alloc((size_t)C_ * C_ * 2);
    float*  segsum = (float*)alloc((size_t)B_ * SEG_ * T_ * 4);
    // Aliased region: phase-1 splits and SF never live simultaneously
    char* shared_base = (char*)alloc((size_t)B_ * T_ * T_ * 4);   // 33.55 MB
    bf16_t* x_hi = (bf16_t*)shared_base;
    bf16_t* x_lo = (bf16_t*)(shared_base + MC2);
    bf16_t* w_hi = (bf16_t*)(shared_base + 2 * MC2);
    bf16_t* w_lo = (bf16_t*)(shared_base + 2 * MC2 + (size_t)N3_ * C_ * 2);
    float*  SF   = (float*)shared_base;
    bf16_t* vt   = kw_hi;   // alias: vt_kernel runs after s_gemm's last read

    int nx = M_ * C_, nw = N3_ * C_, np = C_ * C_;
    int ntot = nx + nw + np;
    prep_kernel<<<dim3((ntot + 255) / 256), 256, 0, stream>>>(
        x, w_attn, w_proj, x_hi, x_lo, w_hi, w_lo, wp_b, nx, nw, np);

    qkv_gemm<<<dim3(M_ / 128, N3_ / 128), 512, 65536, stream>>>(
        x_hi, x_lo, w_hi, w_lo, b_attn, sel_w,
        q_hi, q_lo, kw_hi, kw_lo, k_b, v_b);
    s_gemm<<<dim3(136, 1, B_), 512, 65536, stream>>>(
        q_hi, q_lo, kw_hi, kw_lo, SF, segsum);
    vt_kernel<<<dim3(T_ / 64, H_, B_), 256, 0, stream>>>(v_b, vt);
    scan_apply<<<dim3(B_ * SEG_ * T_ / 256), 256, 0, stream>>>(SF, segsum);
    attn_kernel<<<dim3(T_ / 64, H_, B_), 256, 0, stream>>>(q_hi, k_b, vt, SF, y_b);
    proj_gemm<<<dim3(M_ / 128, C_ / 128), 512, 32768, stream>>>(y_b, wp_b, b_proj, out);
}

// Round 17
// 254.890 us; speedup vs baseline: 1.0109x; 1.0109x over previous
//
#include <hip/hip_runtime.h>

#define B_   2
#define T_   2048
#define C_   768
#define H_   12
#define HD_  64
#define M_   (B_ * T_)    // 4096 rows
#define N3_  (3 * C_)     // 2304
#define KB_  (C_ * 2)     // 1536 bytes per row (bf16)

typedef __bf16 bf16_t;
typedef bf16_t bf16x8 __attribute__((ext_vector_type(8)));
typedef float  floatx4 __attribute__((ext_vector_type(4)));

__device__ inline floatx4 mfma_bf16(bf16x8 a, bf16x8 b, floatx4 c) {
    return __builtin_amdgcn_mfma_f32_16x16x32_bf16(a, b, c, 0, 0, 0);
}

__device__ __forceinline__ void async_copy16(const void* g, void* l) {
    __builtin_amdgcn_global_load_lds(
        (const __attribute__((address_space(1))) void*)g,
        (__attribute__((address_space(3))) void*)l, 16, 0, 0);
}

__device__ __forceinline__ bf16x8 frag_read(const char* ldsbase, int row, int quad) {
    int slot = quad ^ ((row >> 1) & 3);
    return *(const bf16x8*)(ldsbase + row * 64 + slot * 16);
}

// ---------------------------------------------------------------------------
// 128x128-tile GEMM mainloop, DOUBLE-BUFFERED, 512 THREADS (8 waves).
// ---------------------------------------------------------------------------
template<bool TRIPLE>
__device__ __forceinline__ void gemm_loop8(
    const char* Ah, const char* Al, const char* Bh, const char* Bl,
    char* lds, floatx4 (&acc)[4][2])
{
    int tid = threadIdx.x, lane = tid & 63, wave = tid >> 6;
    int l15 = lane & 15, quad = lane >> 4;
    int wr = wave >> 2, wc = wave & 3;
    const int PH = TRIPLE ? 32768 : 16384;
    auto stage1 = [&](const char* tile, char* base, int k0) {
        int p = tid;                             // 512 x 16B = 8 KB
        int r = p >> 2, slot = p & 3;
        int g = slot ^ ((r >> 1) & 3);
        async_copy16(tile + (size_t)r * KB_ + k0 + g * 16, base + p * 16);
    };
    auto stage = [&](int ph, int k0) {
        char* base = lds + ph * PH;
        stage1(Ah, base, k0);
        stage1(Bh, base + 8192, k0);
        if (TRIPLE) {
            stage1(Al, base + 16384, k0);
            stage1(Bl, base + 24576, k0);
        }
    };
    stage(0, 0);
    int ph = 0;
#pragma unroll 1
    for (int k0 = 0; k0 < KB_; k0 += 64) {       // 32 bf16 per chunk
        __syncthreads();                          // drains stage(ph)
        if (k0 + 64 < KB_) stage(ph ^ 1, k0 + 64);
        char* base = lds + ph * PH;
        bf16x8 ah[4], al[4], bh[2], bl[2];
#pragma unroll
        for (int t = 0; t < 4; ++t) {
            ah[t] = frag_read(base, wr * 64 + t * 16 + l15, quad);
            if (TRIPLE)
                al[t] = frag_read(base + 16384, wr * 64 + t * 16 + l15, quad);
        }
#pragma unroll
        for (int t = 0; t < 2; ++t) {
            bh[t] = frag_read(base + 8192, wc * 32 + t * 16 + l15, quad);
            if (TRIPLE)
                bl[t] = frag_read(base + 24576, wc * 32 + t * 16 + l15, quad);
        }
#pragma unroll
        for (int mi = 0; mi < 4; ++mi)
#pragma unroll
            for (int ni = 0; ni < 2; ++ni) {
                acc[mi][ni] = mfma_bf16(ah[mi], bh[ni], acc[mi][ni]);
                if (TRIPLE) {
                    acc[mi][ni] = mfma_bf16(ah[mi], bl[ni], acc[mi][ni]);
                    acc[mi][ni] = mfma_bf16(al[mi], bh[ni], acc[mi][ni]);
                }
            }
        ph ^= 1;
    }
}

// ---------------------------------------------------------------------------
// K0 (fused): split x -> x_hi/lo, split w_attn -> w_hi/lo, convert w_proj.
// ---------------------------------------------------------------------------
__global__ __launch_bounds__(256) void prep_kernel(
    const float* __restrict__ x, const float* __restrict__ w_attn,
    const float* __restrict__ w_proj,
    bf16_t* __restrict__ x_hi, bf16_t* __restrict__ x_lo,
    bf16_t* __restrict__ w_hi, bf16_t* __restrict__ w_lo,
    bf16_t* __restrict__ wp_b, int nx, int nw, int np)
{
    int gid = blockIdx.x * 256 + threadIdx.x;
    if (gid < nx) {
        float f = x[gid];
        bf16_t h = (bf16_t)f;
        x_hi[gid] = h;
        x_lo[gid] = (bf16_t)(f - (float)h);
    } else if (gid < nx + nw) {
        int i = gid - nx;
        float f = w_attn[i];
        bf16_t h = (bf16_t)f;
        w_hi[i] = h;
        w_lo[i] = (bf16_t)(f - (float)h);
    } else if (gid < nx + nw + np) {
        int i = gid - nx - nw;
        wp_b[i] = (bf16_t)w_proj[i];
    }
}

// ---------------------------------------------------------------------------
// K1: qkv = x @ w_attn^T + b_attn (512 threads).  q/k bf16x3; v bf16.
// ---------------------------------------------------------------------------
__global__ __launch_bounds__(512) void qkv_gemm(
    const bf16_t* __restrict__ x_hi, const bf16_t* __restrict__ x_lo,
    const bf16_t* __restrict__ w_hi, const bf16_t* __restrict__ w_lo,
    const float* __restrict__ bias, const float* __restrict__ selw,
    bf16_t* __restrict__ q_hi, bf16_t* __restrict__ q_lo,
    bf16_t* __restrict__ kw_hi, bf16_t* __restrict__ kw_lo,
    bf16_t* __restrict__ k_b, bf16_t* __restrict__ v_b)
{
    extern __shared__ char lds[];
    int m0 = blockIdx.x * 128, n0 = blockIdx.y * 128;
    floatx4 acc[4][2];
#pragma unroll
    for (int i = 0; i < 4; ++i)
#pragma unroll
        for (int j = 0; j < 2; ++j) acc[i][j] = (floatx4){0.f, 0.f, 0.f, 0.f};
    if (n0 >= 2 * C_) {
        gemm_loop8<false>((const char*)(x_hi + (size_t)m0 * C_), nullptr,
                          (const char*)(w_hi + (size_t)n0 * C_), nullptr, lds, acc);
    } else {
        gemm_loop8<true>((const char*)(x_hi + (size_t)m0 * C_),
                         (const char*)(x_lo + (size_t)m0 * C_),
                         (const char*)(w_hi + (size_t)n0 * C_),
                         (const char*)(w_lo + (size_t)n0 * C_), lds, acc);
    }

    int tid = threadIdx.x, lane = tid & 63, wave = tid >> 6;
    int l15 = lane & 15, quad = lane >> 4;
    int wr = wave >> 2, wc = wave & 3;
    int cb = n0 + wc * 32;
#pragma unroll
    for (int ni = 0; ni < 2; ++ni) {
        int col = cb + ni * 16 + l15;
        float bb = bias[col];
#pragma unroll
        for (int mi = 0; mi < 4; ++mi)
#pragma unroll
            for (int r = 0; r < 4; ++r) {
                int row = m0 + wr * 64 + mi * 16 + quad * 4 + r;
                float v = acc[mi][ni][r] + bb;
                if (cb < C_) {
                    float vs = v * 0.125f;
                    bf16_t h = (bf16_t)vs;
                    q_hi[(size_t)row * C_ + col] = h;
                    q_lo[(size_t)row * C_ + col] = (bf16_t)(vs - (float)h);
                } else if (cb < 2 * C_) {
                    int c2 = col - C_;
                    k_b[(size_t)row * C_ + c2] = (bf16_t)v;
                    float kw = v * selw[c2 >> 6];
                    bf16_t h = (bf16_t)kw;
                    kw_hi[(size_t)row * C_ + c2] = h;
                    kw_lo[(size_t)row * C_ + c2] = (bf16_t)(kw - (float)h);
                } else {
                    v_b[(size_t)row * C_ + (col - 2 * C_)] = (bf16_t)v;
                }
            }
    }
}

// ---------------------------------------------------------------------------
// K2: triangular s_gemm (512 threads), fused segsum.
// ---------------------------------------------------------------------------
#define SEG_    16
#define SEGLEN_ (T_ / SEG_)  // 128

__global__ __launch_bounds__(512) void s_gemm(
    const bf16_t* __restrict__ q_hi, const bf16_t* __restrict__ q_lo,
    const bf16_t* __restrict__ kw_hi, const bf16_t* __restrict__ kw_lo,
    float* __restrict__ SF, float* __restrict__ segsum)
{
    extern __shared__ char lds[];
    int t = blockIdx.x, b = blockIdx.z;
    int it = (int)((sqrtf(8.f * t + 1.f) - 1.f) * 0.5f);
    while ((it + 1) * (it + 2) / 2 <= t) ++it;
    while (it * (it + 1) / 2 > t) --it;
    int jt = t - it * (it + 1) / 2;               // jt <= it
    int i0 = it * 128, j0 = jt * 128;
    float* out = SF + (size_t)b * T_ * T_;

    floatx4 acc[4][2];
#pragma unroll
    for (int i = 0; i < 4; ++i)
#pragma unroll
        for (int j = 0; j < 2; ++j) acc[i][j] = (floatx4){0.f, 0.f, 0.f, 0.f};
    size_t arow = ((size_t)b * T_ + i0) * C_;
    size_t brow = ((size_t)b * T_ + j0) * C_;
    gemm_loop8<true>((const char*)(q_hi + arow), (const char*)(q_lo + arow),
                     (const char*)(kw_hi + brow), (const char*)(kw_lo + brow),
                     lds, acc);

    int tid = threadIdx.x, lane = tid & 63, wave = tid >> 6;
    int l15 = lane & 15, quad = lane >> 4;
    int wr = wave >> 2, wc = wave & 3;
    float colsum[2] = {0.f, 0.f};
#pragma unroll
    for (int ni = 0; ni < 2; ++ni) {
        int j = j0 + wc * 32 + ni * 16 + l15;
#pragma unroll
        for (int mi = 0; mi < 4; ++mi)
#pragma unroll
            for (int r = 0; r < 4; ++r) {
                int i = i0 + wr * 64 + mi * 16 + quad * 4 + r;
                float s = acc[mi][ni][r];
                s = (j >= 1 && j < i) ? fmaxf(s, 0.f) : 0.f;
                out[(size_t)i * T_ + j] = s;
                colsum[ni] += s;
            }
    }
#pragma unroll
    for (int ni = 0; ni < 2; ++ni) {
        colsum[ni] += __shfl_xor(colsum[ni], 16);
        colsum[ni] += __shfl_xor(colsum[ni], 32);
    }
    float* red = (float*)lds;                     // [wr][128] (phase-0 area)
    if (quad == 0) {
#pragma unroll
        for (int ni = 0; ni < 2; ++ni)
            red[wr * 128 + wc * 32 + ni * 16 + l15] = colsum[ni];
    }
    __syncthreads();
    if (tid < 128) {
        float ssum = red[tid] + red[128 + tid];
        segsum[((size_t)b * SEG_ + it) * T_ + j0 + tid] = ssum;
    }
}

// ---------------------------------------------------------------------------
// K4: scan_apply with inline exclusive segment prefix from raw segsum.
// ---------------------------------------------------------------------------
__global__ __launch_bounds__(256) void scan_apply(
    float* __restrict__ SF, const float* __restrict__ segsum)
{
    int gid  = blockIdx.x * 256 + threadIdx.x;
    int j    = gid & (T_ - 1);
    int rest = gid >> 11;
    int seg  = rest & (SEG_ - 1);
    int b    = rest >> 4;
    if (seg * SEGLEN_ + SEGLEN_ - 1 < j) return;
    float run = 0.f;
    for (int s = 0; s < seg; ++s) {
        float v = (s * SEGLEN_ + SEGLEN_ - 1 <= j) ? 0.f
                : segsum[((size_t)b * SEG_ + s) * T_ + j];
        run += v;
    }
    float* col = SF + (size_t)b * T_ * T_ + (size_t)(seg * SEGLEN_) * T_ + j;
#pragma unroll 4
    for (int i = 0; i < SEGLEN_; ++i) {
        float s = col[(size_t)i * T_];
        s = (seg * SEGLEN_ + i > j) ? s : 0.f;
        col[(size_t)i * T_] = run;
        run += s;
    }
}

// ---------------------------------------------------------------------------
// K5b: V -> V^T  (per (b,h): [T][64] -> [64][T]).
// ---------------------------------------------------------------------------
__global__ __launch_bounds__(256) void vt_kernel(
    const bf16_t* __restrict__ v_b, bf16_t* __restrict__ vt)
{
    __shared__ bf16_t tile[64][72];
    int t0 = blockIdx.x * 64, h = blockIdx.y, b = blockIdx.z;
    int tid = threadIdx.x;
    int r = tid >> 2, sl = tid & 3;
    const bf16_t* src = v_b + ((size_t)(b * T_ + t0 + r)) * C_ + h * HD_ + sl * 16;
    *(int4*)&tile[r][sl * 16]     = *(const int4*)src;
    *(int4*)&tile[r][sl * 16 + 8] = *(const int4*)(src + 8);
    __syncthreads();
    int hd = tid >> 2, q = tid & 3;
#pragma unroll
    for (int half = 0; half < 2; ++half) {
        int c0 = (q * 2 + half) * 8;
        union { int4 i4; bf16_t e[8]; } u;
#pragma unroll
        for (int kk = 0; kk < 8; ++kk) u.e[kk] = tile[c0 + kk][hd];
        *(int4*)(vt + ((size_t)(b * H_ + h) * HD_ + hd) * T_ + t0 + c0) = u.i4;
    }
}

// ---------------------------------------------------------------------------
// K6 (v8): SPLIT-J flash attention.  Round-16 analysis: time == longest
// block's serial barrier chain (32 iters x ~4400cyc), immune to sum-balance.
// Fixed-normalizer partials are ADDITIVE -> tiles bi>=16 split into two
// <=16-iteration blocks writing raw f32 (O,l) partials; merge_kernel combines.
// Grid x=48: job map (g=x>>4, u=x&15), per-CU round-robin triple {g0,g1,g2}
// with same u sums to 33 iters:
//   g0: first-half of tile 16+u (16 it) / g1: tile u (u+1 it) /
//   g2: second-half of tile 31-u (16-u it)
// Softmax fully C-layout (fixed-M: exp is elementwise, zero in-loop shfl;
// l reduction deferred to epilogue) -> f32 LS buffer deleted, only bf16 P
// roundtrips.  LDS 40960 -> 4 blocks/CU resident (grid is 4.5/CU).
// ---------------------------------------------------------------------------
__global__ __launch_bounds__(256) void attn_kernel(
    const bf16_t* __restrict__ q_b, const bf16_t* __restrict__ k_b,
    const bf16_t* __restrict__ vt_g, const float* __restrict__ FF,
    bf16_t* __restrict__ y_b, float* __restrict__ opart,
    float* __restrict__ lpart)
{
    __shared__ __align__(16) char KL[2][8192];
    __shared__ __align__(16) char VL[2][8192];
    __shared__ __align__(16) bf16_t PB[4][1024];   // per-wave P [16][64] bf16

    int tid = threadIdx.x, lane = tid & 63, wave = tid >> 6;
    int l15 = lane & 15, quad = lane >> 4;
    int u = blockIdx.x & 15, g = blockIdx.x >> 4;
    int tile, jlo, jhi, half;
    bool split;
    if (g == 0)      { tile = 16 + u; jlo = 0;  jhi = 15;       half = 0; split = true;  }
    else if (g == 1) { tile = u;      jlo = 0;  jhi = u;        half = 0; split = false; }
    else             { tile = 31 - u; jlo = 16; jhi = 31 - u;   half = 1; split = true;  }
    int h = blockIdx.y, b = blockIdx.z;
    int i0w = tile * 64 + wave * 16;
    const floatx4 fzero = {0.f, 0.f, 0.f, 0.f};

    const bf16_t* qrow = q_b + ((size_t)b * T_ + i0w + l15) * C_ + h * HD_;
    bf16x8 qa0 = *(const bf16x8*)(qrow + quad * 8);
    bf16x8 qa1 = *(const bf16x8*)(qrow + 32 + quad * 8);

    const bf16_t* kbase = k_b + (size_t)b * T_ * C_ + h * HD_;
    const bf16_t* vbase = vt_g + (size_t)(b * H_ + h) * HD_ * T_;
    // C-layout FF row pointers: row = i0w + quad*4 + r, col = j + l15
    const float* fpr[4];
#pragma unroll
    for (int r = 0; r < 4; ++r)
        fpr[r] = FF + ((size_t)b * T_ + i0w + quad * 4 + r) * T_ + jlo * 64 + l15;

    auto stage = [&](int ph, int j0) {
#pragma unroll
        for (int i = 0; i < 2; ++i) {
            int p = (wave * 2 + i) * 64 + lane;
            int r = p >> 3, sp = p & 7, s = sp ^ (r & 7);
            async_copy16(kbase + (size_t)(j0 + r) * C_ + s * 8, &KL[ph][p * 16]);
        }
#pragma unroll
        for (int i = 0; i < 2; ++i) {
            int p = (wave * 2 + i) * 64 + lane;
            int r = p >> 3, sp = p & 7, s = sp ^ (r & 7);
            async_copy16(vbase + (size_t)r * T_ + j0 + s * 8, &VL[ph][p * 16]);
        }
    };

    float l_lane[4] = {0.f, 0.f, 0.f, 0.f};
    floatx4 O[4];
#pragma unroll
    for (int nt = 0; nt < 4; ++nt) O[nt] = fzero;

    stage(0, jlo * 64);
    int ph = 0;
#pragma unroll 1
    for (int jc = jlo; jc <= jhi; ++jc) {
        __syncthreads();
        if (jc < jhi) stage(ph ^ 1, (jc + 1) * 64);

        // FF C-layout: 16 dword loads (4 rows x 4 col-subtiles)
        float ff[4][4];
#pragma unroll
        for (int r = 0; r < 4; ++r) {
#pragma unroll
            for (int s = 0; s < 4; ++s) ff[s][r] = fpr[r][s * 16];
            fpr[r] += 64;
        }
        // QK^T -> C-layout
        floatx4 pc[4];
#pragma unroll
        for (int s = 0; s < 4; ++s) {
            int r = s * 16 + l15;
            bf16x8 k0 = *(const bf16x8*)&KL[ph][r * 128 + ((quad     ^ (r & 7)) * 16)];
            bf16x8 k1 = *(const bf16x8*)&KL[ph][r * 128 + (((quad+4) ^ (r & 7)) * 16)];
            floatx4 p = mfma_bf16(qa0, k0, fzero);
            pc[s] = mfma_bf16(qa1, k1, p);
        }
        // p = exp(qk - ff - 20), elementwise; mask only in diagonal chunk
        bool diag = (jc * 64 + 63 > i0w);
        float p[4][4];
#pragma unroll
        for (int s = 0; s < 4; ++s)
#pragma unroll
            for (int r = 0; r < 4; ++r) {
                float lg = pc[s][r] - ff[s][r] - 20.f;
                if (diag) {
                    int i = i0w + quad * 4 + r;
                    int j = jc * 64 + s * 16 + l15;
                    lg = (j <= i) ? lg : -__builtin_inff();
                }
                p[s][r] = __expf(lg);
            }
#pragma unroll
        for (int r = 0; r < 4; ++r)
            l_lane[r] += (p[0][r] + p[1][r]) + (p[2][r] + p[3][r]);

        // P: C-layout -> bf16 LDS (16B-chunk XOR swizzle) -> A-frags
        bf16_t* Pw = &PB[wave][0];
#pragma unroll
        for (int s = 0; s < 4; ++s)
#pragma unroll
            for (int r = 0; r < 4; ++r) {
                int rr = quad * 4 + r;
                int ch = (s * 2 + (l15 >> 3)) ^ (rr & 7);
                Pw[rr * 64 + ch * 8 + (l15 & 7)] = (bf16_t)p[s][r];
            }
        asm volatile("s_waitcnt lgkmcnt(0)" ::: "memory");
        int xk = l15 & 7;
        bf16x8 pa0 = *(const bf16x8*)&Pw[l15 * 64 + ((quad ^ xk) * 8)];
        bf16x8 pa1 = *(const bf16x8*)&Pw[l15 * 64 + (((4 + quad) ^ xk) * 8)];
#pragma unroll
        for (int nt = 0; nt < 4; ++nt) {
            int r = nt * 16 + l15;
            bf16x8 v0 = *(const bf16x8*)&VL[ph][r * 128 + ((quad     ^ (r & 7)) * 16)];
            bf16x8 v1 = *(const bf16x8*)&VL[ph][r * 128 + (((quad+4) ^ (r & 7)) * 16)];
            O[nt] = mfma_bf16(pa0, v0, O[nt]);
            O[nt] = mfma_bf16(pa1, v1, O[nt]);
        }
        ph ^= 1;
    }

    // deferred l reduction across the 16 l15-lanes of each quad
#pragma unroll
    for (int r = 0; r < 4; ++r)
#pragma unroll
        for (int d = 1; d < 16; d <<= 1)
            l_lane[r] += __shfl_xor(l_lane[r], d);

    if (!split) {
#pragma unroll
        for (int r = 0; r < 4; ++r) {
            float inv = 1.f / l_lane[r];
            int i = i0w + quad * 4 + r;
#pragma unroll
            for (int nt = 0; nt < 4; ++nt)
                y_b[((size_t)b * T_ + i) * C_ + h * HD_ + nt * 16 + l15] =
                    (bf16_t)(O[nt][r] * inv);
        }
    } else {
        size_t ob = ((((size_t)(b * H_ + h) * 16 + (tile - 16)) * 2 + half) * 4096);
#pragma unroll
        for (int r = 0; r < 4; ++r) {
            int rl = wave * 16 + quad * 4 + r;   // row within the 64-row tile
#pragma unroll
            for (int nt = 0; nt < 4; ++nt)
                opart[ob + (size_t)rl * 64 + nt * 16 + l15] = O[nt][r];
        }
        if (l15 == 0) {
            size_t lb = (((size_t)(b * H_ + h) * 16 + (tile - 16)) * 2 + half) * 64;
#pragma unroll
            for (int r = 0; r < 4; ++r)
                lpart[lb + wave * 16 + quad * 4 + r] = l_lane[r];
        }
    }
}

// ---------------------------------------------------------------------------
// K6b: merge split-tile partials: y = (O0+O1)/(l0+l1).
// ---------------------------------------------------------------------------
__global__ __launch_bounds__(256) void merge_kernel(
    const float* __restrict__ opart, const float* __restrict__ lpart,
    bf16_t* __restrict__ y_b)
{
    int tt = blockIdx.x, h = blockIdx.y, b = blockIdx.z;
    size_t b0 = (((size_t)(b * H_ + h) * 16 + tt) * 2) * 4096;
    size_t l0 = (((size_t)(b * H_ + h) * 16 + tt) * 2) * 64;
    int tile = 16 + tt;
#pragma unroll 4
    for (int e = threadIdx.x; e < 4096; e += 256) {
        int row = e >> 6, col = e & 63;
        float l = lpart[l0 + row] + lpart[l0 + 64 + row];
        float o = opart[b0 + e] + opart[b0 + 4096 + e];
        y_b[((size_t)b * T_ + tile * 64 + row) * C_ + h * HD_ + col] =
            (bf16_t)(o / l);
    }
}

// ---------------------------------------------------------------------------
// K7: out = y @ w_proj^T + b_proj  (512 threads, dbuf 32 KB)
// ---------------------------------------------------------------------------
__global__ __launch_bounds__(512) void proj_gemm(
    const bf16_t* __restrict__ y_b, const bf16_t* __restrict__ wp_b,
    const float* __restrict__ bias, float* __restrict__ out)
{
    extern __shared__ char lds[];
    int m0 = blockIdx.x * 128, n0 = blockIdx.y * 128;
    floatx4 acc[4][2];
#pragma unroll
    for (int i = 0; i < 4; ++i)
#pragma unroll
        for (int j = 0; j < 2; ++j) acc[i][j] = (floatx4){0.f, 0.f, 0.f, 0.f};
    gemm_loop8<false>((const char*)(y_b + (size_t)m0 * C_), nullptr,
                      (const char*)(wp_b + (size_t)n0 * C_), nullptr, lds, acc);

    int tid = threadIdx.x, lane = tid & 63, wave = tid >> 6;
    int l15 = lane & 15, quad = lane >> 4;
    int wr = wave >> 2, wc = wave & 3;
#pragma unroll
    for (int ni = 0; ni < 2; ++ni) {
        int col = n0 + wc * 32 + ni * 16 + l15;
        float bb = bias[col];
#pragma unroll
        for (int mi = 0; mi < 4; ++mi)
#pragma unroll
            for (int r = 0; r < 4; ++r)
                out[(size_t)(m0 + wr * 64 + mi * 16 + quad * 4 + r) * C_ + col] =
                    acc[mi][ni][r] + bb;
    }
}

// ---------------------------------------------------------------------------
extern "C" void kernel_launch(void* const* d_in, const int* in_sizes, int n_in,
                              void* d_out, int out_size, void* d_ws, size_t ws_size,
                              hipStream_t stream)
{
    const float* x      = (const float*)d_in[0];
    const float* w_attn = (const float*)d_in[1];
    const float* b_attn = (const float*)d_in[2];
    const float* w_proj = (const float*)d_in[3];
    const float* b_proj = (const float*)d_in[4];
    const float* sel_w  = (const float*)d_in[5];
    float* out = (float*)d_out;

    char* ws = (char*)d_ws;
    size_t off = 0;
    auto alloc = [&](size_t bytes) {
        void* p = ws + off;
        off += (bytes + 255) & ~(size_t)255;
        return p;
    };
    const size_t MC2 = (size_t)M_ * C_ * 2;          // 6.29 MB
    // Live-through-attn region
    bf16_t* q_hi   = (bf16_t*)alloc(MC2);
    bf16_t* kw_hi  = (bf16_t*)alloc(MC2);   // dead after s_gemm -> reused as vt
    bf16_t* k_b    = (bf16_t*)alloc(MC2);
    bf16_t* y_b    = (bf16_t*)alloc(MC2);
    bf16_t* wp_b   = (bf16_t*)alloc((size_t)C_ * C_ * 2);
    float*  segsum = (float*)alloc((size_t)B_ * SEG_ * T_ * 4);
    // Dead-by-attn group (contiguous 18.9 MB): q_lo, kw_lo, v_b.
    // Aliased by attn partials: opart 12.58 MB + lpart 0.20 MB.
    char* dead_base = (char*)alloc(3 * MC2);
    bf16_t* q_lo  = (bf16_t*)dead_base;
    bf16_t* kw_lo = (bf16_t*)(dead_base + MC2);
    bf16_t* v_b   = (bf16_t*)(dead_base + 2 * MC2);
    float*  opart = (float*)dead_base;
    float*  lpart = (float*)(dead_base + (size_t)B_ * H_ * 16 * 2 * 4096 * 4);
    // Aliased region: phase-1 splits and SF never live simultaneously
    char* shared_base = (char*)alloc((size_t)B_ * T_ * T_ * 4);   // 33.55 MB
    bf16_t* x_hi = (bf16_t*)shared_base;
    bf16_t* x_lo = (bf16_t*)(shared_base + MC2);
    bf16_t* w_hi = (bf16_t*)(shared_base + 2 * MC2);
    bf16_t* w_lo = (bf16_t*)(shared_base + 2 * MC2 + (size_t)N3_ * C_ * 2);
    float*  SF   = (float*)shared_base;
    bf16_t* vt   = kw_hi;   // alias: vt_kernel runs after s_gemm's last read

    int nx = M_ * C_, nw = N3_ * C_, np = C_ * C_;
    int ntot = nx + nw + np;
    prep_kernel<<<dim3((ntot + 255) / 256), 256, 0, stream>>>(
        x, w_attn, w_proj, x_hi, x_lo, w_hi, w_lo, wp_b, nx, nw, np);

    qkv_gemm<<<dim3(M_ / 128, N3_ / 128), 512, 65536, stream>>>(
        x_hi, x_lo, w_hi, w_lo, b_attn, sel_w,
        q_hi, q_lo, kw_hi, kw_lo, k_b, v_b);
    s_gemm<<<dim3(136, 1, B_), 512, 65536, stream>>>(
        q_hi, q_lo, kw_hi, kw_lo, SF, segsum);
    vt_kernel<<<dim3(T_ / 64, H_, B_), 256, 0, stream>>>(v_b, vt);
    scan_apply<<<dim3(B_ * SEG_ * T_ / 256), 256, 0, stream>>>(SF, segsum);
    attn_kernel<<<dim3(48, H_, B_), 256, 0, stream>>>(
        q_hi, k_b, vt, SF, y_b, opart, lpart);
    merge_kernel<<<dim3(16, H_, B_), 256, 0, stream>>>(opart, lpart, y_b);
    proj_gemm<<<dim3(M_ / 128, C_ / 128), 512, 32768, stream>>>(y_b, wp_b, b_proj, out);
}